// Round 1
// baseline (1712.306 us; speedup 1.0000x reference)
//
#include <hip/hip_runtime.h>

#define BB 8
#define NN 20000
#define EE 320000
#define DD 64
#define ROWS (BB*NN)
#define EPS 1e-5f
#define CH 64  // readout chunks per batch

// ---------------- encoder: h = relu(x @ W_in + b_in) ----------------
__global__ __launch_bounds__(256) void k_encoder(const float* __restrict__ x,
    const float* __restrict__ Win, const float* __restrict__ bin,
    float* __restrict__ h) {
  int idx = blockIdx.x * 256 + threadIdx.x;  // over ROWS*DD
  int d = idx & 63;
  int r = idx >> 6;
  if (r < ROWS) {
    float v = fmaf(x[r], Win[d], bin[d]);
    h[idx] = v > 0.f ? v : 0.f;
  }
}

// ---------------- degree ----------------
__global__ __launch_bounds__(256) void k_deg(const int* __restrict__ dst,
                                             int* __restrict__ cnt) {
  int e = blockIdx.x * 256 + threadIdx.x;
  if (e < EE) atomicAdd(&cnt[dst[e]], 1);
}

__global__ __launch_bounds__(256) void k_invdeg(const int* __restrict__ cnt,
                                                float* __restrict__ invdeg) {
  int n = blockIdx.x * 256 + threadIdx.x;
  if (n < NN) {
    int c = cnt[n];
    invdeg[n] = 1.0f / (float)(c > 1 ? c : 1);
  }
}

// ---------------- scatter-add of raw h rows: agg[b,dst] += h[b,src] ----------------
__global__ __launch_bounds__(256) void k_scatter(const float* __restrict__ h,
    const int* __restrict__ src, const int* __restrict__ dst,
    float* __restrict__ agg) {
  int wid = (blockIdx.x * 256 + threadIdx.x) >> 6;  // wave per edge
  int lane = threadIdx.x & 63;
  if (wid >= EE) return;
  int s = src[wid], t = dst[wid];
  const float* hp = h + (size_t)s * DD + lane;
  float* ap = agg + (size_t)t * DD + lane;
  float v[BB];
#pragma unroll
  for (int b = 0; b < BB; ++b) v[b] = hp[(size_t)b * NN * DD];
#pragma unroll
  for (int b = 0; b < BB; ++b) atomicAdd(ap + (size_t)b * NN * DD, v[b]);
}

// ---------------- fused node update: z = h + relu(h@Ws + (agg@Wm)/deg + bias); LN ----------------
__global__ __launch_bounds__(256) void k_node(const float* __restrict__ h,
    const float* __restrict__ agg, const float* __restrict__ invdeg,
    const float* __restrict__ Ws, const float* __restrict__ Wm,
    const float* __restrict__ bias, const float* __restrict__ g,
    const float* __restrict__ be, float* __restrict__ hout,
    int nwaves_total) {
  __shared__ float sh[4][DD], sa[4][DD];
  int lane = threadIdx.x & 63;
  int w = threadIdx.x >> 6;
  int gwave = blockIdx.x * 4 + w;
  // per-lane weight column d=lane held in registers (static indices after unroll)
  float wsc[DD], wmc[DD];
#pragma unroll
  for (int k = 0; k < DD; ++k) {
    wsc[k] = Ws[k * DD + lane];
    wmc[k] = Wm[k * DD + lane];
  }
  float bv = bias[lane], gv = g[lane], bev = be[lane];
  int iters = (ROWS + nwaves_total - 1) / nwaves_total;
  for (int i = 0; i < iters; ++i) {
    int r = gwave + i * nwaves_total;
    bool valid = r < ROWS;
    float hv = 0.f, av = 0.f;
    if (valid) {
      hv = h[(size_t)r * DD + lane];
      int b = r / NN;
      int n = r - b * NN;
      av = agg[(size_t)r * DD + lane] * invdeg[n];
    }
    sh[w][lane] = hv;
    sa[w][lane] = av;
    __syncthreads();
    float accs = 0.f, acca = 0.f;
#pragma unroll
    for (int k4 = 0; k4 < DD / 4; ++k4) {
      float4 hh = *(const float4*)&sh[w][k4 * 4];
      float4 aa = *(const float4*)&sa[w][k4 * 4];
      accs = fmaf(hh.x, wsc[k4 * 4 + 0], accs);
      acca = fmaf(aa.x, wmc[k4 * 4 + 0], acca);
      accs = fmaf(hh.y, wsc[k4 * 4 + 1], accs);
      acca = fmaf(aa.y, wmc[k4 * 4 + 1], acca);
      accs = fmaf(hh.z, wsc[k4 * 4 + 2], accs);
      acca = fmaf(aa.z, wmc[k4 * 4 + 2], acca);
      accs = fmaf(hh.w, wsc[k4 * 4 + 3], accs);
      acca = fmaf(aa.w, wmc[k4 * 4 + 3], acca);
    }
    __syncthreads();
    if (valid) {
      float t = accs + acca + bv;
      float z = hv + (t > 0.f ? t : 0.f);
      // LayerNorm over the 64 lanes (= feature dim)
      float s = z;
#pragma unroll
      for (int off = 32; off > 0; off >>= 1) s += __shfl_xor(s, off, 64);
      float mu = s * (1.0f / 64.0f);
      float dz = z - mu;
      float v2 = dz * dz;
#pragma unroll
      for (int off = 32; off > 0; off >>= 1) v2 += __shfl_xor(v2, off, 64);
      float var = v2 * (1.0f / 64.0f);
      float o = fmaf(gv * dz, rsqrtf(var + EPS), bev);
      hout[(size_t)r * DD + lane] = o;
    }
  }
}

// ---------------- readout partials: per (b, chunk) sum & max over nodes ----------------
__global__ __launch_bounds__(256) void k_reduce(const float* __restrict__ h,
    float* __restrict__ psum, float* __restrict__ pmax) {
  int lane = threadIdx.x & 63;
  int w = threadIdx.x >> 6;
  int b = blockIdx.x / CH;
  int chunk = blockIdx.x % CH;
  const int csz = (NN + CH - 1) / CH;  // 313
  int n0 = chunk * csz;
  int n1 = n0 + csz;
  if (n1 > NN) n1 = NN;
  float s = 0.f, m = -INFINITY;
  for (int n = n0 + w; n < n1; n += 4) {
    float v = h[((size_t)b * NN + n) * DD + lane];
    s += v;
    m = fmaxf(m, v);
  }
  __shared__ float ls[4][DD], lm[4][DD];
  ls[w][lane] = s;
  lm[w][lane] = m;
  __syncthreads();
  if (w == 0) {
    float ss = ls[0][lane] + ls[1][lane] + ls[2][lane] + ls[3][lane];
    float mm = fmaxf(fmaxf(lm[0][lane], lm[1][lane]),
                     fmaxf(lm[2][lane], lm[3][lane]));
    psum[((size_t)b * CH + chunk) * DD + lane] = ss;
    pmax[((size_t)b * CH + chunk) * DD + lane] = mm;
  }
}

// ---------------- final: reduce partials, graph_emb, 2-layer MLP head ----------------
__global__ __launch_bounds__(512) void k_final(const float* __restrict__ psum,
    const float* __restrict__ pmax, const float* __restrict__ Wh1,
    const float* __restrict__ bh1, const float* __restrict__ Wh2,
    const float* __restrict__ bh2, float* __restrict__ out) {
  __shared__ float emb[BB][2 * DD];
  __shared__ float hid[BB][DD];
  int t = threadIdx.x;  // 512 threads = 8 b * 64 d
  int b = t >> 6, d = t & 63;
  float s = 0.f, m = -INFINITY;
  for (int c = 0; c < CH; ++c) {
    s += psum[((size_t)b * CH + c) * DD + d];
    m = fmaxf(m, pmax[((size_t)b * CH + c) * DD + d]);
  }
  emb[b][d] = s * (1.0f / (float)NN);
  emb[b][DD + d] = m;
  __syncthreads();
  float acc = bh1[d];
#pragma unroll
  for (int k = 0; k < 2 * DD; ++k) acc = fmaf(emb[b][k], Wh1[k * DD + d], acc);
  hid[b][d] = acc > 0.f ? acc : 0.f;
  __syncthreads();
  if (d == 0) {
    float o = bh2[0];
    for (int j = 0; j < DD; ++j) o = fmaf(hid[b][j], Wh2[j], o);
    out[b] = o;
  }
}

extern "C" void kernel_launch(void* const* d_in, const int* in_sizes, int n_in,
                              void* d_out, int out_size, void* d_ws, size_t ws_size,
                              hipStream_t stream) {
  const float* x    = (const float*)d_in[0];
  const int*   ei   = (const int*)d_in[1];
  const float* Win  = (const float*)d_in[2];
  const float* bin  = (const float*)d_in[3];
  const float* Ws1  = (const float*)d_in[4];
  const float* Wm1  = (const float*)d_in[5];
  const float* bias1= (const float*)d_in[6];
  const float* g1   = (const float*)d_in[7];
  const float* be1  = (const float*)d_in[8];
  const float* Ws2  = (const float*)d_in[9];
  const float* Wm2  = (const float*)d_in[10];
  const float* bias2= (const float*)d_in[11];
  const float* g2   = (const float*)d_in[12];
  const float* be2  = (const float*)d_in[13];
  const float* Wh1  = (const float*)d_in[14];
  const float* bh1  = (const float*)d_in[15];
  const float* Wh2  = (const float*)d_in[16];
  const float* bh2  = (const float*)d_in[17];
  float* out = (float*)d_out;

  const int* src = ei;
  const int* dst = ei + EE;

  // workspace carve-up (all 256B aligned)
  char* ws = (char*)d_ws;
  size_t off = 0;
  auto carve = [&](size_t bytes) {
    void* p = ws + off;
    off = (off + bytes + 255) & ~(size_t)255;
    return p;
  };
  const size_t hbytes = sizeof(float) * (size_t)ROWS * DD;  // 40.96 MB
  float* hA     = (float*)carve(hbytes);
  float* hB     = (float*)carve(hbytes);
  float* agg    = (float*)carve(hbytes);
  int*   cnt    = (int*)carve(sizeof(int) * NN);
  float* invdeg = (float*)carve(sizeof(float) * NN);
  float* psum   = (float*)carve(sizeof(float) * (size_t)BB * CH * DD);
  float* pmax   = (float*)carve(sizeof(float) * (size_t)BB * CH * DD);

  const int NODE_BLOCKS = 640;
  const int NODE_WAVES = NODE_BLOCKS * 4;

  // encoder
  k_encoder<<<(ROWS * DD + 255) / 256, 256, 0, stream>>>(x, Win, bin, hA);

  // degree (shared by both layers)
  hipMemsetAsync(cnt, 0, sizeof(int) * NN, stream);
  k_deg<<<(EE + 255) / 256, 256, 0, stream>>>(dst, cnt);
  k_invdeg<<<(NN + 255) / 256, 256, 0, stream>>>(cnt, invdeg);

  // ---- layer 1 ----
  hipMemsetAsync(agg, 0, hbytes, stream);
  k_scatter<<<(EE * 64) / 256, 256, 0, stream>>>(hA, src, dst, agg);
  k_node<<<NODE_BLOCKS, 256, 0, stream>>>(hA, agg, invdeg, Ws1, Wm1, bias1, g1,
                                          be1, hB, NODE_WAVES);

  // ---- layer 2 ----
  hipMemsetAsync(agg, 0, hbytes, stream);
  k_scatter<<<(EE * 64) / 256, 256, 0, stream>>>(hB, src, dst, agg);
  k_node<<<NODE_BLOCKS, 256, 0, stream>>>(hB, agg, invdeg, Ws2, Wm2, bias2, g2,
                                          be2, hA, NODE_WAVES);

  // ---- readout + head ----
  k_reduce<<<BB * CH, 256, 0, stream>>>(hA, psum, pmax);
  k_final<<<1, 512, 0, stream>>>(psum, pmax, Wh1, bh1, Wh2, bh2, out);
}

// Round 2
// 502.516 us; speedup vs baseline: 3.4075x; 3.4075x over previous
//
#include <hip/hip_runtime.h>

#define BB 8
#define NN 20000
#define EE 320000
#define DD 64
#define ROWS (BB*NN)
#define EPS 1e-5f
#define CH 64  // readout chunks per batch

__device__ __forceinline__ float bcastf(float v, int l) {
  return __uint_as_float(__builtin_amdgcn_readlane(__float_as_uint(v), l));
}
__device__ __forceinline__ int bcasti(int v, int l) {
  return __builtin_amdgcn_readlane(v, l);
}

// ---------------- encoder: h = relu(x @ W_in + b_in), D_IN=1 ----------------
__global__ __launch_bounds__(256) void k_encoder(const float* __restrict__ x,
    const float* __restrict__ Win, const float* __restrict__ bin,
    float* __restrict__ h) {
  int idx = blockIdx.x * 256 + threadIdx.x;  // over ROWS*DD
  int d = idx & 63;
  int r = idx >> 6;
  if (r < ROWS) {
    float v = fmaf(x[r], Win[d], bin[d]);
    h[idx] = v > 0.f ? v : 0.f;
  }
}

// ---------------- degree ----------------
__global__ __launch_bounds__(256) void k_deg(const int* __restrict__ dst,
                                             int* __restrict__ cnt) {
  int e = blockIdx.x * 256 + threadIdx.x;
  if (e < EE) atomicAdd(&cnt[dst[e]], 1);
}

__global__ __launch_bounds__(256) void k_invdeg(const int* __restrict__ cnt,
                                                float* __restrict__ invdeg) {
  int n = blockIdx.x * 256 + threadIdx.x;
  if (n < NN) {
    int c = cnt[n];
    invdeg[n] = 1.0f / (float)(c > 1 ? c : 1);
  }
}

// ---------------- exclusive scan of cnt -> rowptr (single block) ----------------
__global__ __launch_bounds__(1024) void k_scan(const int* __restrict__ cnt,
                                               int* __restrict__ rowptr) {
  __shared__ int part[1024];
  int t = threadIdx.x;
  const int PER = (NN + 1023) / 1024;  // 20
  int base = t * PER;
  int s = 0;
#pragma unroll
  for (int i = 0; i < PER; ++i) {
    int idx = base + i;
    s += (idx < NN) ? cnt[idx] : 0;
  }
  part[t] = s;
  __syncthreads();
  for (int off = 1; off < 1024; off <<= 1) {
    int v = (t >= off) ? part[t - off] : 0;
    __syncthreads();
    part[t] += v;
    __syncthreads();
  }
  int run = (t > 0) ? part[t - 1] : 0;
#pragma unroll
  for (int i = 0; i < PER; ++i) {
    int idx = base + i;
    if (idx <= NN) rowptr[idx] = run;
    run += (idx < NN) ? cnt[idx] : 0;
  }
}

// ---------------- fill CSR buckets: nbr[rowptr[dst]+k] = src ----------------
__global__ __launch_bounds__(256) void k_fill(const int* __restrict__ src,
    const int* __restrict__ dst, const int* __restrict__ rowptr,
    int* __restrict__ cur, int* __restrict__ nbr) {
  int e = blockIdx.x * 256 + threadIdx.x;
  if (e < EE) {
    int t = dst[e];
    int pos = rowptr[t] + atomicAdd(&cur[t], 1);
    nbr[pos] = src[e];
  }
}

// ---------------- pull-mode aggregation: agg[b,n,:] = (sum_{s in N(n)} h[b,s,:]) / deg ----------------
__global__ __launch_bounds__(256) void k_agg(const float* __restrict__ h,
    const int* __restrict__ rowptr, const int* __restrict__ nbr,
    const float* __restrict__ invdeg, float* __restrict__ agg) {
  int wid = (blockIdx.x * 256 + threadIdx.x) >> 6;  // wave per node
  int lane = threadIdx.x & 63;
  if (wid >= NN) return;
  int n = wid;
  int s0 = rowptr[n], s1 = rowptr[n + 1];
  float acc[BB];
#pragma unroll
  for (int b = 0; b < BB; ++b) acc[b] = 0.f;
  for (int base = s0; base < s1; base += 64) {
    int m = s1 - base;
    if (m > 64) m = 64;
    int idxv = (base + lane < s1) ? nbr[base + lane] : 0;
    for (int j = 0; j < m; ++j) {
      int s = bcasti(idxv, j);
      const float* hp = h + (size_t)s * DD + lane;
#pragma unroll
      for (int b = 0; b < BB; ++b) acc[b] += hp[(size_t)b * NN * DD];
    }
  }
  float iv = invdeg[n];
  float* ap = agg + (size_t)n * DD + lane;
#pragma unroll
  for (int b = 0; b < BB; ++b) ap[(size_t)b * NN * DD] = acc[b] * iv;
}

// ---------------- fused node update (no LDS, readlane broadcast) ----------------
// z = h + relu(h@Ws + agg@Wm + bias); out = LayerNorm(z)
__global__ __launch_bounds__(256) void k_node(const float* __restrict__ h,
    const float* __restrict__ agg, const float* __restrict__ Ws,
    const float* __restrict__ Wm, const float* __restrict__ bias,
    const float* __restrict__ g, const float* __restrict__ be,
    float* __restrict__ hout, int nwaves_total) {
  int lane = threadIdx.x & 63;
  int gwave = blockIdx.x * 4 + (threadIdx.x >> 6);
  // per-lane weight column d=lane in registers (128 VGPR)
  float wsc[DD], wmc[DD];
#pragma unroll
  for (int k = 0; k < DD; ++k) {
    wsc[k] = Ws[k * DD + lane];
    wmc[k] = Wm[k * DD + lane];
  }
  float bv = bias[lane], gv = g[lane], bev = be[lane];
  for (int r = gwave; r < ROWS; r += nwaves_total) {
    float hv = h[(size_t)r * DD + lane];
    float av = agg[(size_t)r * DD + lane];
    float accs = 0.f, acca = 0.f;
#pragma unroll
    for (int k = 0; k < DD; ++k) {
      accs = fmaf(bcastf(hv, k), wsc[k], accs);
      acca = fmaf(bcastf(av, k), wmc[k], acca);
    }
    float t = accs + acca + bv;
    float z = hv + (t > 0.f ? t : 0.f);
    // LayerNorm over the 64 lanes (= feature dim)
    float s = z;
#pragma unroll
    for (int off = 32; off > 0; off >>= 1) s += __shfl_xor(s, off, 64);
    float mu = s * (1.0f / 64.0f);
    float dz = z - mu;
    float v2 = dz * dz;
#pragma unroll
    for (int off = 32; off > 0; off >>= 1) v2 += __shfl_xor(v2, off, 64);
    float var = v2 * (1.0f / 64.0f);
    hout[(size_t)r * DD + lane] = fmaf(gv * dz, rsqrtf(var + EPS), bev);
  }
}

// ---------------- readout partials: per (b, chunk) sum & max over nodes ----------------
__global__ __launch_bounds__(256) void k_reduce(const float* __restrict__ h,
    float* __restrict__ psum, float* __restrict__ pmax) {
  int lane = threadIdx.x & 63;
  int w = threadIdx.x >> 6;
  int b = blockIdx.x / CH;
  int chunk = blockIdx.x % CH;
  const int csz = (NN + CH - 1) / CH;  // 313
  int n0 = chunk * csz;
  int n1 = n0 + csz;
  if (n1 > NN) n1 = NN;
  float s = 0.f, m = -INFINITY;
  for (int n = n0 + w; n < n1; n += 4) {
    float v = h[((size_t)b * NN + n) * DD + lane];
    s += v;
    m = fmaxf(m, v);
  }
  __shared__ float ls[4][DD], lm[4][DD];
  ls[w][lane] = s;
  lm[w][lane] = m;
  __syncthreads();
  if (w == 0) {
    float ss = ls[0][lane] + ls[1][lane] + ls[2][lane] + ls[3][lane];
    float mm = fmaxf(fmaxf(lm[0][lane], lm[1][lane]),
                     fmaxf(lm[2][lane], lm[3][lane]));
    psum[((size_t)b * CH + chunk) * DD + lane] = ss;
    pmax[((size_t)b * CH + chunk) * DD + lane] = mm;
  }
}

// ---------------- final: reduce partials, graph_emb, 2-layer MLP head ----------------
__global__ __launch_bounds__(512) void k_final(const float* __restrict__ psum,
    const float* __restrict__ pmax, const float* __restrict__ Wh1,
    const float* __restrict__ bh1, const float* __restrict__ Wh2,
    const float* __restrict__ bh2, float* __restrict__ out) {
  __shared__ float emb[BB][2 * DD];
  __shared__ float hid[BB][DD];
  int t = threadIdx.x;  // 512 threads = 8 b * 64 d
  int b = t >> 6, d = t & 63;
  float s = 0.f, m = -INFINITY;
  for (int c = 0; c < CH; ++c) {
    s += psum[((size_t)b * CH + c) * DD + d];
    m = fmaxf(m, pmax[((size_t)b * CH + c) * DD + d]);
  }
  emb[b][d] = s * (1.0f / (float)NN);
  emb[b][DD + d] = m;
  __syncthreads();
  float acc = bh1[d];
#pragma unroll
  for (int k = 0; k < 2 * DD; ++k) acc = fmaf(emb[b][k], Wh1[k * DD + d], acc);
  hid[b][d] = acc > 0.f ? acc : 0.f;
  __syncthreads();
  if (d == 0) {
    float o = bh2[0];
    for (int j = 0; j < DD; ++j) o = fmaf(hid[b][j], Wh2[j], o);
    out[b] = o;
  }
}

extern "C" void kernel_launch(void* const* d_in, const int* in_sizes, int n_in,
                              void* d_out, int out_size, void* d_ws, size_t ws_size,
                              hipStream_t stream) {
  const float* x    = (const float*)d_in[0];
  const int*   ei   = (const int*)d_in[1];
  const float* Win  = (const float*)d_in[2];
  const float* bin  = (const float*)d_in[3];
  const float* Ws1  = (const float*)d_in[4];
  const float* Wm1  = (const float*)d_in[5];
  const float* bias1= (const float*)d_in[6];
  const float* g1   = (const float*)d_in[7];
  const float* be1  = (const float*)d_in[8];
  const float* Ws2  = (const float*)d_in[9];
  const float* Wm2  = (const float*)d_in[10];
  const float* bias2= (const float*)d_in[11];
  const float* g2   = (const float*)d_in[12];
  const float* be2  = (const float*)d_in[13];
  const float* Wh1  = (const float*)d_in[14];
  const float* bh1  = (const float*)d_in[15];
  const float* Wh2  = (const float*)d_in[16];
  const float* bh2  = (const float*)d_in[17];
  float* out = (float*)d_out;

  const int* src = ei;
  const int* dst = ei + EE;

  char* ws = (char*)d_ws;
  size_t off = 0;
  auto carve = [&](size_t bytes) {
    void* p = ws + off;
    off = (off + bytes + 255) & ~(size_t)255;
    return p;
  };
  const size_t hbytes = sizeof(float) * (size_t)ROWS * DD;  // 40.96 MB
  float* hA     = (float*)carve(hbytes);
  float* hB     = (float*)carve(hbytes);
  float* agg    = (float*)carve(hbytes);
  int*   cnt    = (int*)carve(sizeof(int) * NN);      // also reused as 'cur'
  int*   rowptr = (int*)carve(sizeof(int) * (NN + 1));
  int*   nbr    = (int*)carve(sizeof(int) * EE);
  float* invdeg = (float*)carve(sizeof(float) * NN);
  float* psum   = (float*)carve(sizeof(float) * (size_t)BB * CH * DD);
  float* pmax   = (float*)carve(sizeof(float) * (size_t)BB * CH * DD);

  const int NODE_BLOCKS = 1024;
  const int NODE_WAVES = NODE_BLOCKS * 4;

  // encoder
  k_encoder<<<(ROWS * DD + 255) / 256, 256, 0, stream>>>(x, Win, bin, hA);

  // CSR build (once; shared by both layers)
  hipMemsetAsync(cnt, 0, sizeof(int) * NN, stream);
  k_deg<<<(EE + 255) / 256, 256, 0, stream>>>(dst, cnt);
  k_invdeg<<<(NN + 255) / 256, 256, 0, stream>>>(cnt, invdeg);
  k_scan<<<1, 1024, 0, stream>>>(cnt, rowptr);
  hipMemsetAsync(cnt, 0, sizeof(int) * NN, stream);  // reuse as cursor
  k_fill<<<(EE + 255) / 256, 256, 0, stream>>>(src, dst, rowptr, cnt, nbr);

  // ---- layer 1 ----
  k_agg<<<(NN + 3) / 4, 256, 0, stream>>>(hA, rowptr, nbr, invdeg, agg);
  k_node<<<NODE_BLOCKS, 256, 0, stream>>>(hA, agg, Ws1, Wm1, bias1, g1, be1,
                                          hB, NODE_WAVES);

  // ---- layer 2 ----
  k_agg<<<(NN + 3) / 4, 256, 0, stream>>>(hB, rowptr, nbr, invdeg, agg);
  k_node<<<NODE_BLOCKS, 256, 0, stream>>>(hB, agg, Ws2, Wm2, bias2, g2, be2,
                                          hA, NODE_WAVES);

  // ---- readout + head ----
  k_reduce<<<BB * CH, 256, 0, stream>>>(hA, psum, pmax);
  k_final<<<1, 512, 0, stream>>>(psum, pmax, Wh1, bh1, Wh2, bh2, out);
}